// Round 1
// baseline (83.630 us; speedup 1.0000x reference)
//
#include <hip/hip_runtime.h>

// BahdanauAttnDecoderRNN single-step decode, MI355X.
// Key observation: reference applies softmax over a size-1 axis => attn_weights
// are exactly 1.0; attn_W/attn_b and the score matvec are dead code.
// attn_applied = column-sum(encoder_outputs).
// Everything else is batch-1 matvec: memory-bound, ~177 MB total reads.

namespace {
constexpr int H = 1024;
constexpr int V = 32000;
constexpr int S = 2048;
}

__device__ __forceinline__ float wave_sum(float v) {
#pragma unroll
    for (int off = 32; off > 0; off >>= 1) v += __shfl_xor(v, off, 64);
    return v;
}

// K1: partial column sums of encoder_outputs. grid = nchunk blocks x 256 thr,
// each block sums `rows` rows over all 1024 columns (float4 per thread).
__global__ void k_colsum(const float* __restrict__ enc, float* __restrict__ part, int rows) {
    const int c4 = threadIdx.x;  // 256 threads * 4 cols = 1024 cols
    const float4* e = (const float4*)enc + (size_t)blockIdx.x * rows * (H / 4);
    float4 acc = make_float4(0.f, 0.f, 0.f, 0.f);
    for (int r = 0; r < rows; ++r) {
        float4 v = e[(size_t)r * (H / 4) + c4];
        acc.x += v.x; acc.y += v.y; acc.z += v.z; acc.w += v.w;
    }
    ((float4*)part)[(size_t)blockIdx.x * (H / 4) + c4] = acc;
}

// K2: finish attn colsum reduce, build rnn_input = relu([emb_row, colsum]),
// write attn_weights = 1.0. grid = 8 x 256 (2048 threads).
__global__ void k_finish(const float* __restrict__ part, int nchunk,
                         const float* __restrict__ emb,
                         const int* __restrict__ word,
                         float* __restrict__ rnn, float* __restrict__ out) {
    const int j = blockIdx.x * blockDim.x + threadIdx.x;  // 0..2047
    float v;
    if (j < H) {
        v = emb[(size_t)word[0] * H + j];
    } else {
        const int c = j - H;
        float s = 0.f;
        for (int k = 0; k < nchunk; ++k) s += part[(size_t)k * H + c];
        v = s;
    }
    rnn[j] = v > 0.f ? v : 0.f;
    out[V + H + j] = 1.0f;  // attn_weights (exactly ones per reference)
}

// K3: GRU matvecs. One wave per output row (3072 rows). block 256 = 4 waves.
__global__ __launch_bounds__(256) void k_gru(
    const float* __restrict__ Wih, const float* __restrict__ Whh,
    const float* __restrict__ bih, const float* __restrict__ bhh,
    const float* __restrict__ h, const float* __restrict__ rnn,
    float* __restrict__ gi, float* __restrict__ gh) {
    const int lane = threadIdx.x & 63;
    const int row = blockIdx.x * 4 + (threadIdx.x >> 6);  // < 3072
    const float4* wi = (const float4*)Wih + (size_t)row * (2 * H / 4);
    const float4* xr = (const float4*)rnn;
    float a = 0.f;
#pragma unroll
    for (int it = 0; it < 8; ++it) {
        float4 w = wi[it * 64 + lane], x = xr[it * 64 + lane];
        a += w.x * x.x + w.y * x.y + w.z * x.z + w.w * x.w;
    }
    const float4* wh = (const float4*)Whh + (size_t)row * (H / 4);
    const float4* xh = (const float4*)h;
    float b = 0.f;
#pragma unroll
    for (int it = 0; it < 4; ++it) {
        float4 w = wh[it * 64 + lane], x = xh[it * 64 + lane];
        b += w.x * x.x + w.y * x.y + w.z * x.z + w.w * x.w;
    }
    a = wave_sum(a);
    b = wave_sum(b);
    if (lane == 0) {
        gi[row] = a + bih[row];
        gh[row] = b + bhh[row];
    }
}

// K4: GRU gates -> h_new. grid 4 x 256.
__global__ void k_gates(const float* __restrict__ gi, const float* __restrict__ gh,
                        const float* __restrict__ h, float* __restrict__ hnew,
                        float* __restrict__ out) {
    const int j = blockIdx.x * blockDim.x + threadIdx.x;  // 0..1023
    const float r = 1.f / (1.f + expf(-(gi[j] + gh[j])));
    const float z = 1.f / (1.f + expf(-(gi[H + j] + gh[H + j])));
    const float n = tanhf(gi[2 * H + j] + r * gh[2 * H + j]);
    const float hv = (1.f - z) * n + z * h[j];
    hnew[j] = hv;
    out[V + j] = hv;  // second output
}

// K5: logits = out_W @ h_new + out_b. One wave per row, 32000 rows.
// h_new staged in LDS. Writes raw logits into d_out[0..V).
__global__ __launch_bounds__(256) void k_logits(
    const float* __restrict__ W, const float* __restrict__ b,
    const float* __restrict__ hnew, float* __restrict__ out) {
    __shared__ float4 sh[H / 4];
    sh[threadIdx.x] = ((const float4*)hnew)[threadIdx.x];
    __syncthreads();
    const int lane = threadIdx.x & 63;
    const int row = blockIdx.x * 4 + (threadIdx.x >> 6);  // < 32000
    const float4* wr = (const float4*)W + (size_t)row * (H / 4);
    float a = 0.f;
#pragma unroll
    for (int it = 0; it < 4; ++it) {
        float4 w = wr[it * 64 + lane];
        float4 x = sh[it * 64 + lane];
        a += w.x * x.x + w.y * x.y + w.z * x.z + w.w * x.w;
    }
    a = wave_sum(a);
    if (lane == 0) out[row] = a + b[row];
}

// K6: single-block reduce: max + log(sum(exp(x-max))). Logits are L2-resident.
__global__ void k_smreduce(const float* __restrict__ out, float* __restrict__ red) {
    __shared__ float warp[16];
    __shared__ float bcast;
    const int tid = threadIdx.x;  // 1024 threads = 16 waves
    float m = -3.4e38f;
    for (int i = tid; i < V; i += 1024) m = fmaxf(m, out[i]);
#pragma unroll
    for (int off = 32; off > 0; off >>= 1) m = fmaxf(m, __shfl_xor(m, off, 64));
    if ((tid & 63) == 0) warp[tid >> 6] = m;
    __syncthreads();
    if (tid == 0) {
        float t = warp[0];
        for (int k = 1; k < 16; ++k) t = fmaxf(t, warp[k]);
        bcast = t;
    }
    __syncthreads();
    const float M = bcast;
    float s = 0.f;
    for (int i = tid; i < V; i += 1024) s += expf(out[i] - M);
    s = wave_sum(s);
    if ((tid & 63) == 0) warp[tid >> 6] = s;
    __syncthreads();
    if (tid == 0) {
        float t = 0.f;
        for (int k = 0; k < 16; ++k) t += warp[k];
        red[0] = M;
        red[1] = logf(t);
    }
}

// K7: in-place log-softmax write. 125 x 256 = 32000 exactly.
__global__ void k_lsm(float* __restrict__ out, const float* __restrict__ red) {
    const int i = blockIdx.x * blockDim.x + threadIdx.x;
    out[i] = out[i] - red[0] - red[1];
}

extern "C" void kernel_launch(void* const* d_in, const int* in_sizes, int n_in,
                              void* d_out, int out_size, void* d_ws, size_t ws_size,
                              hipStream_t stream) {
    const int*   word = (const int*)d_in[0];
    const float* h    = (const float*)d_in[1];
    const float* enc  = (const float*)d_in[2];
    const float* emb  = (const float*)d_in[3];
    // d_in[4] attn_W, d_in[5] attn_b: dead code in reference (softmax over size-1 axis)
    const float* Wih  = (const float*)d_in[6];
    const float* Whh  = (const float*)d_in[7];
    const float* bih  = (const float*)d_in[8];
    const float* bhh  = (const float*)d_in[9];
    const float* Wout = (const float*)d_in[10];
    const float* bout = (const float*)d_in[11];
    float* out = (float*)d_out;
    float* ws  = (float*)d_ws;

    // pick colsum chunk count to fit workspace (deterministic given ws_size)
    int nchunk = 128;
    while (nchunk > 1) {
        size_t need = ((size_t)nchunk * H + 2 * H + 3 * H + 3 * H + H + 2) * sizeof(float);
        if (need <= ws_size) break;
        nchunk >>= 1;
    }
    const int rows = S / nchunk;

    float* part = ws;
    float* rnn  = ws + (size_t)nchunk * H;
    float* gi   = rnn + 2 * H;
    float* gh   = gi + 3 * H;
    float* hnew = gh + 3 * H;
    float* red  = hnew + H;

    k_colsum<<<nchunk, 256, 0, stream>>>(enc, part, rows);
    k_finish<<<8, 256, 0, stream>>>(part, nchunk, emb, word, rnn, out);
    k_gru<<<3072 / 4, 256, 0, stream>>>(Wih, Whh, bih, bhh, h, rnn, gi, gh);
    k_gates<<<4, 256, 0, stream>>>(gi, gh, h, hnew, out);
    k_logits<<<V / 4, 256, 0, stream>>>(Wout, bout, hnew, out);
    k_smreduce<<<1, 1024, 0, stream>>>(out, red);
    k_lsm<<<V / 256, 256, 0, stream>>>(out, red);
}

// Round 2
// 62.527 us; speedup vs baseline: 1.3375x; 1.3375x over previous
//
#include <hip/hip_runtime.h>

// BahdanauAttnDecoderRNN single-step decode, MI355X.
// Dead code in reference: softmax over a size-1 axis => attn_weights == 1.0,
// so attn_W/attn_b/scores are unused and attn_applied = colsum(encoder_outputs).
// All live work is batch-1 matvec: ~178 MB reads, memory-bound (~30 us roofline).
// This version: memset + 4 fused kernels (was 7) to cut launch/tail overhead.
//   K1: colsum partials (atomicAdd) + gh matvec + emb-half of gi + attn ones
//   K2: colsum-half of gi (rnn2 staged in LDS)
//   K3: h_new (redundant per block, LDS) + logits matvec + softmax partials
//   K4: global softmax reduce (redundant per block) + in-place log-softmax

namespace {
constexpr int H = 1024;
constexpr int V = 32000;
constexpr int S = 2048;
constexpr int CS_BLKS = 128;   // colsum blocks, 16 rows each
constexpr int MV_BLKS = 768;   // gh+gi1 blocks, 4 rows each (3072 rows)
constexpr int K2_BLKS = 192;   // 16 rows each -> 3072
constexpr int K3_BLKS = 2000;  // 16 rows each -> 32000
}

__device__ __forceinline__ float wave_sum(float v) {
#pragma unroll
    for (int off = 32; off > 0; off >>= 1) v += __shfl_xor(v, off, 64);
    return v;
}
__device__ __forceinline__ float wave_max(float v) {
#pragma unroll
    for (int off = 32; off > 0; off >>= 1) v = fmaxf(v, __shfl_xor(v, off, 64));
    return v;
}

// K1: blocks [0,128): colsum partial->atomicAdd; [128,896): gh + gi_emb rows;
//     block 896: attn_weights ones.
__global__ __launch_bounds__(256) void k1(
    const float* __restrict__ enc, const float* __restrict__ Whh,
    const float* __restrict__ Wih, const float* __restrict__ bih,
    const float* __restrict__ bhh, const float* __restrict__ h,
    const float* __restrict__ emb, const int* __restrict__ word,
    float* __restrict__ colsum, float* __restrict__ gi, float* __restrict__ gh,
    float* __restrict__ out) {
    const int b = blockIdx.x, t = threadIdx.x;
    if (b < CS_BLKS) {
        // rows [b*16, b*16+16), thread t owns float4-column t (cols 4t..4t+3)
        const float4* e = (const float4*)enc + (size_t)b * 16 * (H / 4) + t;
        float4 acc = make_float4(0.f, 0.f, 0.f, 0.f);
#pragma unroll
        for (int r = 0; r < 16; ++r) {
            float4 v = e[r * (H / 4)];
            acc.x += v.x; acc.y += v.y; acc.z += v.z; acc.w += v.w;
        }
        atomicAdd(&colsum[t * 4 + 0], acc.x);
        atomicAdd(&colsum[t * 4 + 1], acc.y);
        atomicAdd(&colsum[t * 4 + 2], acc.z);
        atomicAdd(&colsum[t * 4 + 3], acc.w);
    } else if (b < CS_BLKS + MV_BLKS) {
        const int lane = t & 63;
        const int row = (b - CS_BLKS) * 4 + (t >> 6);  // < 3072
        const float4* wh = (const float4*)Whh + (size_t)row * (H / 4);
        const float4* xh = (const float4*)h;
        const float4* wi = (const float4*)Wih + (size_t)row * (2 * H / 4);  // first half
        const float4* er = (const float4*)emb + (size_t)word[0] * (H / 4);
        float ah = 0.f, ai = 0.f;
#pragma unroll
        for (int it = 0; it < 4; ++it) {
            const int idx = it * 64 + lane;
            float4 w = wh[idx], x = xh[idx];
            ah += w.x * x.x + w.y * x.y + w.z * x.z + w.w * x.w;
            float4 wv = wi[idx], e4 = er[idx];
            e4.x = fmaxf(e4.x, 0.f); e4.y = fmaxf(e4.y, 0.f);
            e4.z = fmaxf(e4.z, 0.f); e4.w = fmaxf(e4.w, 0.f);
            ai += wv.x * e4.x + wv.y * e4.y + wv.z * e4.z + wv.w * e4.w;
        }
        ah = wave_sum(ah);
        ai = wave_sum(ai);
        if (lane == 0) {
            gh[row] = ah + bhh[row];
            gi[row] = ai + bih[row];  // partial: + colsum-half added in K2
        }
    } else {
        // attn_weights are exactly 1.0 (softmax over size-1 axis)
#pragma unroll
        for (int k = 0; k < 8; ++k) out[V + H + k * 256 + t] = 1.0f;
    }
}

// K2: gi[row] += Wih[row, H:2H] . relu(colsum). 192 blocks x 16 rows.
__global__ __launch_bounds__(256) void k2(
    const float* __restrict__ Wih, const float* __restrict__ colsum,
    float* __restrict__ gi) {
    __shared__ float4 rnn2[H / 4];
    const int t = threadIdx.x;
    float4 c = ((const float4*)colsum)[t];
    c.x = fmaxf(c.x, 0.f); c.y = fmaxf(c.y, 0.f);
    c.z = fmaxf(c.z, 0.f); c.w = fmaxf(c.w, 0.f);
    rnn2[t] = c;
    __syncthreads();
    const int lane = t & 63;
    const int w = t >> 6;
#pragma unroll
    for (int i = 0; i < 4; ++i) {
        const int row = blockIdx.x * 16 + w * 4 + i;  // < 3072
        const float4* wr = (const float4*)Wih + (size_t)row * (2 * H / 4) + (H / 4);
        float a = 0.f;
#pragma unroll
        for (int it = 0; it < 4; ++it) {
            const int idx = it * 64 + lane;
            float4 wv = wr[idx], x = rnn2[idx];
            a += wv.x * x.x + wv.y * x.y + wv.z * x.z + wv.w * x.w;
        }
        a = wave_sum(a);
        if (lane == 0) gi[row] += a;
    }
}

// K3: per block: h_new into LDS (redundant), then 16 logits rows, then
// per-block softmax partials (max, sum exp(l-max)).
__global__ __launch_bounds__(256) void k3(
    const float* __restrict__ gi, const float* __restrict__ gh,
    const float* __restrict__ h, const float* __restrict__ W,
    const float* __restrict__ bo, float* __restrict__ out,
    float* __restrict__ partmax, float* __restrict__ partsum) {
    __shared__ float hnew[H];
    __shared__ float blogit[16];
    const int t = threadIdx.x;
#pragma unroll
    for (int q = 0; q < 4; ++q) {
        const int j = q * 256 + t;
        const float r = 1.f / (1.f + expf(-(gi[j] + gh[j])));
        const float z = 1.f / (1.f + expf(-(gi[H + j] + gh[H + j])));
        const float n = tanhf(gi[2 * H + j] + r * gh[2 * H + j]);
        const float hv = (1.f - z) * n + z * h[j];
        hnew[j] = hv;
        if (blockIdx.x == 0) out[V + j] = hv;  // hidden output
    }
    __syncthreads();
    const int lane = t & 63;
    const int w = t >> 6;
    const float4* hn4 = (const float4*)hnew;
#pragma unroll
    for (int i = 0; i < 4; ++i) {
        const int row = blockIdx.x * 16 + w * 4 + i;  // < 32000
        const float4* wr = (const float4*)W + (size_t)row * (H / 4);
        float a = 0.f;
#pragma unroll
        for (int it = 0; it < 4; ++it) {
            const int idx = it * 64 + lane;
            float4 wv = wr[idx], x = hn4[idx];
            a += wv.x * x.x + wv.y * x.y + wv.z * x.z + wv.w * x.w;
        }
        a = wave_sum(a);
        if (lane == 0) {
            a += bo[row];
            out[row] = a;
            blogit[w * 4 + i] = a;
        }
    }
    __syncthreads();
    if (t == 0) {
        float m = blogit[0];
#pragma unroll
        for (int k = 1; k < 16; ++k) m = fmaxf(m, blogit[k]);
        float s = 0.f;
#pragma unroll
        for (int k = 0; k < 16; ++k) s += expf(blogit[k] - m);
        partmax[blockIdx.x] = m;
        partsum[blockIdx.x] = s;
    }
}

// K4: global (max, log-sum-exp) from 2000 partials (redundant per block),
// then in-place log-softmax. 126 blocks x 256 covers 32000.
__global__ __launch_bounds__(256) void k4(
    const float* __restrict__ pm, const float* __restrict__ ps,
    float* __restrict__ out) {
    __shared__ float sm[4], ss[4];
    __shared__ float bM, bL;
    const int t = threadIdx.x, lane = t & 63, w = t >> 6;
    float m = -3.4e38f;
    for (int k = t; k < K3_BLKS; k += 256) m = fmaxf(m, pm[k]);
    m = wave_max(m);
    if (lane == 0) sm[w] = m;
    __syncthreads();
    if (t == 0) bM = fmaxf(fmaxf(sm[0], sm[1]), fmaxf(sm[2], sm[3]));
    __syncthreads();
    const float M = bM;
    float s = 0.f;
    for (int k = t; k < K3_BLKS; k += 256) s += ps[k] * expf(pm[k] - M);
    s = wave_sum(s);
    if (lane == 0) ss[w] = s;
    __syncthreads();
    if (t == 0) bL = logf(ss[0] + ss[1] + ss[2] + ss[3]);
    __syncthreads();
    const float L = bL;
    const int idx = blockIdx.x * 256 + t;
    if (idx < V) out[idx] = out[idx] - M - L;
}

extern "C" void kernel_launch(void* const* d_in, const int* in_sizes, int n_in,
                              void* d_out, int out_size, void* d_ws, size_t ws_size,
                              hipStream_t stream) {
    const int*   word = (const int*)d_in[0];
    const float* h    = (const float*)d_in[1];
    const float* enc  = (const float*)d_in[2];
    const float* emb  = (const float*)d_in[3];
    // d_in[4] attn_W, d_in[5] attn_b: dead (softmax over size-1 axis)
    const float* Wih  = (const float*)d_in[6];
    const float* Whh  = (const float*)d_in[7];
    const float* bih  = (const float*)d_in[8];
    const float* bhh  = (const float*)d_in[9];
    const float* Wout = (const float*)d_in[10];
    const float* bout = (const float*)d_in[11];
    float* out = (float*)d_out;
    float* ws  = (float*)d_ws;

    float* colsum = ws;                  // [1024]
    float* gi     = colsum + H;          // [3072]
    float* gh     = gi + 3 * H;          // [3072]
    float* pmax   = gh + 3 * H;          // [2000]
    float* psum   = pmax + K3_BLKS;      // [2000]

    hipMemsetAsync(colsum, 0, H * sizeof(float), stream);
    k1<<<CS_BLKS + MV_BLKS + 1, 256, 0, stream>>>(enc, Whh, Wih, bih, bhh, h,
                                                  emb, word, colsum, gi, gh, out);
    k2<<<K2_BLKS, 256, 0, stream>>>(Wih, colsum, gi);
    k3<<<K3_BLKS, 256, 0, stream>>>(gi, gh, h, Wout, bout, out, pmax, psum);
    k4<<<(V + 255) / 256, 256, 0, stream>>>(pmax, psum, out);
}